// Round 5
// baseline (456.522 us; speedup 1.0000x reference)
//
#include <hip/hip_runtime.h>

// AdaptiveGraph on MI355X.
// Round-4 base + two changes driven by k_main counters (MfmaUtil 7.8%, Occ 21.5%, latency-bound):
//  (1) grids 512->1024: k_main was GRID-limited to 2 blocks/CU (LDS allows 3); k_rowsum to 4.
//  (2) A-stores no longer nontemporal: every __syncthreads drains vmcnt(0); nt stores made
//      that drain wait on HBM-latency completion each iter. Plain stores complete in L2.
// K1: Z = X W^T via bf16 MFMA with hi/lo split; writes Zb [n][h] + ZbT [h][n].
// K2: rowsum[r] = sum_c relu(Z_r . Z_c). 128x512 block tiles, Bfr regs from global.
// K3: recompute S^T tiles, A = relu(S)*rsinv, out += P @ Z via second MFMA, atomicAdd.

#define NR 8192
#define KD 256
#define HD 128

typedef short v8s __attribute__((ext_vector_type(8)));
typedef float v4f __attribute__((ext_vector_type(4)));

static __device__ __forceinline__ ushort f2bf(float f) {
    union { float f; unsigned u; } c; c.f = f;
    unsigned u = c.u;
    u += 0x7fffu + ((u >> 16) & 1u);  // RNE; inputs finite
    return (ushort)(u >> 16);
}
static __device__ __forceinline__ float bf2f(ushort b) {
    union { unsigned u; float f; } c; c.u = ((unsigned)b) << 16; return c.f;
}
static __device__ __forceinline__ unsigned pk2(float a, float b) {
    union { float f; unsigned u; } x, y; x.f = a; y.f = b;
    unsigned ua = x.u + 0x7fffu + ((x.u >> 16) & 1u);
    unsigned ub = y.u + 0x7fffu + ((y.u >> 16) & 1u);
    return (ua >> 16) | (ub & 0xffff0000u);
}

// ---------------- K1: Z = X @ W^T (MFMA, hi/lo bf16 split) ----------------
// grid 256 blocks x 256 thr; block = 32 rows of X; wave owns 32 h-columns.
__global__ __launch_bounds__(256) void k_z(const float* __restrict__ X,
                                           const float* __restrict__ W,
                                           ushort* __restrict__ Zb,
                                           ushort* __restrict__ ZbT) {
    __shared__ ushort Xhi[32][264];  // +8 pad: stride 132 dwords == 4 mod 32 -> 2-way (free)
    __shared__ ushort Xlo[32][264];
    int tid = threadIdx.x, lane = tid & 63, wave = tid >> 6;
    int lm = lane & 15, lq = lane >> 4;
    int n0 = blockIdx.x * 32;
    int hbase = wave * 32;
    v8s Whi[2][8], Wlo[2][8];
#pragma unroll
    for (int hi = 0; hi < 2; ++hi) {
        const float* wp = W + (hbase + hi * 16 + lm) * KD + lq * 8;
#pragma unroll
        for (int ks = 0; ks < 8; ++ks) {
            float4 w0 = *(const float4*)(wp + ks * 32);
            float4 w1 = *(const float4*)(wp + ks * 32 + 4);
            float wv[8] = {w0.x, w0.y, w0.z, w0.w, w1.x, w1.y, w1.z, w1.w};
#pragma unroll
            for (int j = 0; j < 8; ++j) {
                ushort h = f2bf(wv[j]);
                Whi[hi][ks][j] = (short)h;
                Wlo[hi][ks][j] = (short)f2bf(wv[j] - bf2f(h));
            }
        }
    }
#pragma unroll
    for (int t = 0; t < 8; ++t) {
        int idx = tid + t * 256;
        int r = idx >> 6, c4 = (idx & 63) * 4;
        float4 x = *(const float4*)(X + (size_t)(n0 + r) * KD + c4);
        ushort h0 = f2bf(x.x), h1 = f2bf(x.y), h2 = f2bf(x.z), h3 = f2bf(x.w);
        unsigned a = ((unsigned)h0) | ((unsigned)h1 << 16);
        unsigned b = ((unsigned)h2) | ((unsigned)h3 << 16);
        unsigned c = ((unsigned)f2bf(x.x - bf2f(h0))) | ((unsigned)f2bf(x.y - bf2f(h1)) << 16);
        unsigned d = ((unsigned)f2bf(x.z - bf2f(h2))) | ((unsigned)f2bf(x.w - bf2f(h3)) << 16);
        *(uint2*)&Xhi[r][c4] = make_uint2(a, b);
        *(uint2*)&Xlo[r][c4] = make_uint2(c, d);
    }
    __syncthreads();
#pragma unroll
    for (int ni = 0; ni < 2; ++ni) {
        v8s Ah[8], Al[8];
#pragma unroll
        for (int ks = 0; ks < 8; ++ks) {
            Ah[ks] = *(const v8s*)&Xhi[ni * 16 + lm][ks * 32 + lq * 8];
            Al[ks] = *(const v8s*)&Xlo[ni * 16 + lm][ks * 32 + lq * 8];
        }
        v4f acc[2] = {{0.f, 0.f, 0.f, 0.f}, {0.f, 0.f, 0.f, 0.f}};
#pragma unroll
        for (int ks = 0; ks < 8; ++ks)
#pragma unroll
            for (int hi = 0; hi < 2; ++hi) {
                acc[hi] = __builtin_amdgcn_mfma_f32_16x16x32_bf16(Ah[ks], Whi[hi][ks], acc[hi], 0, 0, 0);
                acc[hi] = __builtin_amdgcn_mfma_f32_16x16x32_bf16(Ah[ks], Wlo[hi][ks], acc[hi], 0, 0, 0);
                acc[hi] = __builtin_amdgcn_mfma_f32_16x16x32_bf16(Al[ks], Whi[hi][ks], acc[hi], 0, 0, 0);
            }
#pragma unroll
        for (int hi = 0; hi < 2; ++hi) {
            int h = hbase + hi * 16 + lm;   // D: col=lm -> h, row=lq*4+j -> n
            int nb = n0 + ni * 16 + lq * 4;
            ushort b0 = f2bf(acc[hi][0]), b1 = f2bf(acc[hi][1]);
            ushort b2 = f2bf(acc[hi][2]), b3 = f2bf(acc[hi][3]);
            Zb[(size_t)(nb + 0) * HD + h] = b0;
            Zb[(size_t)(nb + 1) * HD + h] = b1;
            Zb[(size_t)(nb + 2) * HD + h] = b2;
            Zb[(size_t)(nb + 3) * HD + h] = b3;
            *(uint2*)&ZbT[(size_t)h * NR + nb] =
                make_uint2(((unsigned)b0) | ((unsigned)b1 << 16), ((unsigned)b2) | ((unsigned)b3 << 16));
        }
    }
}

// ---------------- K2: rowsum ----------------
// grid 1024 = 64 rb x 16 cs; block tile 128r x (4 iters x 128c); wave = 64r x 64c.
// LDS 34.8 KB -> 4 blocks/CU (grid now provides 4).
__global__ __launch_bounds__(256) void k_rowsum(const ushort* __restrict__ Zb,
                                                float* __restrict__ rowsum) {
    __shared__ ushort ZC[128][136];
    int tid = threadIdx.x, lane = tid & 63, wave = tid >> 6;
    int lm = lane & 15, lq = lane >> 4;
    int rb = blockIdx.x >> 4, cs = blockIdx.x & 15;
    int row0 = rb * 128, cstart = cs * 512;
    int wr2 = wave >> 1, wc2 = wave & 1;
    v8s Bfr[4][4];  // reg-cached row frags (B-operand for S^T), one-time global load
#pragma unroll
    for (int ri = 0; ri < 4; ++ri)
#pragma unroll
        for (int ks = 0; ks < 4; ++ks)
            Bfr[ri][ks] =
                *(const v8s*)(Zb + (size_t)(row0 + wr2 * 64 + ri * 16 + lm) * HD + ks * 32 + lq * 8);
    float rs[4] = {0.f, 0.f, 0.f, 0.f};
    for (int it = 0; it < 4; ++it) {
        int c0 = cstart + it * 128;
        __syncthreads();
#pragma unroll
        for (int t = 0; t < 8; ++t) {
            int idx = tid + t * 256;
            int r = idx >> 4, c8 = (idx & 15) * 8;
            *(uint4*)&ZC[r][c8] = *(const uint4*)(Zb + (size_t)(c0 + r) * HD + c8);
        }
        __syncthreads();
#pragma unroll
        for (int ci = 0; ci < 4; ++ci) {
            v8s Af[4];
#pragma unroll
            for (int ks = 0; ks < 4; ++ks)
                Af[ks] = *(const v8s*)&ZC[wc2 * 64 + ci * 16 + lm][ks * 32 + lq * 8];
            v4f acc[4] = {{0.f,0.f,0.f,0.f},{0.f,0.f,0.f,0.f},{0.f,0.f,0.f,0.f},{0.f,0.f,0.f,0.f}};
#pragma unroll
            for (int ks = 0; ks < 4; ++ks)
#pragma unroll
                for (int ri = 0; ri < 4; ++ri)
                    acc[ri] = __builtin_amdgcn_mfma_f32_16x16x32_bf16(Af[ks], Bfr[ri][ks], acc[ri], 0, 0, 0);
#pragma unroll
            for (int ri = 0; ri < 4; ++ri)
                rs[ri] += fmaxf(acc[ri][0], 0.f) + fmaxf(acc[ri][1], 0.f) +
                          fmaxf(acc[ri][2], 0.f) + fmaxf(acc[ri][3], 0.f);
        }
    }
#pragma unroll
    for (int ri = 0; ri < 4; ++ri) {
        float v = rs[ri];
        v += __shfl_xor(v, 16, 64);
        v += __shfl_xor(v, 32, 64);
        if (lq == 0) atomicAdd(&rowsum[row0 + wr2 * 64 + ri * 16 + lm], v);
    }
}

// ---------------- K3: A write + out accumulate ----------------
// grid 1024 = 128 rb x 8 cs; block tile 64r x (16 iters x 64c); wave = 32r x 32c (S) / 32r x 64h (U).
// LDS 45.1 KB -> 3 blocks/CU (grid now provides >=3). A-stores plain (complete in L2,
// so the pre-barrier vmcnt(0) drain is cheap; nt forced HBM-latency completion).
__global__ __launch_bounds__(256) void k_main(const ushort* __restrict__ Zb,
                                              const ushort* __restrict__ ZbT,
                                              const float* __restrict__ rowsum,
                                              float* __restrict__ outp,
                                              float* __restrict__ Ap) {
    __shared__ ushort ZC[64][136];
    __shared__ ushort ZCT[128][72];  // Z tile [h][c] for U B-operand
    __shared__ ushort PT[64][72];    // normalized A tile bf16, [r][c]
    int tid = threadIdx.x, lane = tid & 63, wave = tid >> 6;
    int lm = lane & 15, lq = lane >> 4;
    int rb = blockIdx.x >> 3, cs = blockIdx.x & 7;
    int row0 = rb * 64, colb = cs * 1024;
    int wr2 = wave >> 1, wc2 = wave & 1;
    v8s Bfr[2][4];  // reg-cached row frags, one-time global load
#pragma unroll
    for (int ri = 0; ri < 2; ++ri)
#pragma unroll
        for (int ks = 0; ks < 4; ++ks)
            Bfr[ri][ks] =
                *(const v8s*)(Zb + (size_t)(row0 + wr2 * 32 + ri * 16 + lm) * HD + ks * 32 + lq * 8);
    float rsv[2];
#pragma unroll
    for (int ri = 0; ri < 2; ++ri)
        rsv[ri] = 1.0f / (rowsum[row0 + wr2 * 32 + ri * 16 + lm] + 1e-6f);
    v4f U[2][4];
#pragma unroll
    for (int ri = 0; ri < 2; ++ri)
#pragma unroll
        for (int hi = 0; hi < 4; ++hi) U[ri][hi] = (v4f){0.f, 0.f, 0.f, 0.f};

    for (int it = 0; it < 16; ++it) {
        int c0 = colb + it * 64;
        __syncthreads();  // prev MFMA2 reads of ZCT/PT done
#pragma unroll
        for (int t = 0; t < 4; ++t) {
            int idx = tid + t * 256;
            int r = idx >> 4, c8 = (idx & 15) * 8;
            *(uint4*)&ZC[r][c8] = *(const uint4*)(Zb + (size_t)(c0 + r) * HD + c8);
        }
#pragma unroll
        for (int t = 0; t < 4; ++t) {
            int idx = tid + t * 256;
            int hh = idx >> 3, cc8 = (idx & 7) * 8;
            *(uint4*)&ZCT[hh][cc8] = *(const uint4*)(ZbT + (size_t)hh * NR + c0 + cc8);
        }
        __syncthreads();
        // S^T = (ZC as A) x (row frags as B): D[m=c][n=r] -> lane: r=lm, c=lq*4+reg
#pragma unroll
        for (int ci = 0; ci < 2; ++ci) {
            v8s Af[4];
#pragma unroll
            for (int ks = 0; ks < 4; ++ks)
                Af[ks] = *(const v8s*)&ZC[wc2 * 32 + ci * 16 + lm][ks * 32 + lq * 8];
            v4f S0 = {0.f, 0.f, 0.f, 0.f}, S1 = {0.f, 0.f, 0.f, 0.f};
#pragma unroll
            for (int ks = 0; ks < 4; ++ks) {
                S0 = __builtin_amdgcn_mfma_f32_16x16x32_bf16(Af[ks], Bfr[0][ks], S0, 0, 0, 0);
                S1 = __builtin_amdgcn_mfma_f32_16x16x32_bf16(Af[ks], Bfr[1][ks], S1, 0, 0, 0);
            }
            int cb = wc2 * 32 + ci * 16 + lq * 4;
            {
                int r = wr2 * 32 + lm;
                v4f av;
                av[0] = fmaxf(S0[0], 0.f) * rsv[0]; av[1] = fmaxf(S0[1], 0.f) * rsv[0];
                av[2] = fmaxf(S0[2], 0.f) * rsv[0]; av[3] = fmaxf(S0[3], 0.f) * rsv[0];
                *(v4f*)(Ap + (size_t)(row0 + r) * NR + c0 + cb) = av;
                *(uint2*)&PT[r][cb] = make_uint2(pk2(av[0], av[1]), pk2(av[2], av[3]));
            }
            {
                int r = wr2 * 32 + 16 + lm;
                v4f av;
                av[0] = fmaxf(S1[0], 0.f) * rsv[1]; av[1] = fmaxf(S1[1], 0.f) * rsv[1];
                av[2] = fmaxf(S1[2], 0.f) * rsv[1]; av[3] = fmaxf(S1[3], 0.f) * rsv[1];
                *(v4f*)(Ap + (size_t)(row0 + r) * NR + c0 + cb) = av;
                *(uint2*)&PT[r][cb] = make_uint2(pk2(av[0], av[1]), pk2(av[2], av[3]));
            }
        }
        __syncthreads();
        // U[r][h] += P[r][c] * Z[c][h]; A = PT frag, B = ZCT frag
#pragma unroll
        for (int ks = 0; ks < 2; ++ks) {
            v8s P0 = *(const v8s*)&PT[wr2 * 32 + lm][ks * 32 + lq * 8];
            v8s P1 = *(const v8s*)&PT[wr2 * 32 + 16 + lm][ks * 32 + lq * 8];
#pragma unroll
            for (int hi = 0; hi < 4; ++hi) {
                v8s Bz = *(const v8s*)&ZCT[wc2 * 64 + hi * 16 + lm][ks * 32 + lq * 8];
                U[0][hi] = __builtin_amdgcn_mfma_f32_16x16x32_bf16(P0, Bz, U[0][hi], 0, 0, 0);
                U[1][hi] = __builtin_amdgcn_mfma_f32_16x16x32_bf16(P1, Bz, U[1][hi], 0, 0, 0);
            }
        }
    }
#pragma unroll
    for (int ri = 0; ri < 2; ++ri)
#pragma unroll
        for (int hi = 0; hi < 4; ++hi)
#pragma unroll
            for (int j = 0; j < 4; ++j)
                atomicAdd(&outp[(size_t)(row0 + wr2 * 32 + ri * 16 + lq * 4 + j) * HD +
                                wc2 * 64 + hi * 16 + lm],
                          U[ri][hi][j]);
}

extern "C" void kernel_launch(void* const* d_in, const int* in_sizes, int n_in,
                              void* d_out, int out_size, void* d_ws, size_t ws_size,
                              hipStream_t stream) {
    (void)in_sizes; (void)n_in; (void)out_size; (void)ws_size;
    const float* X = (const float*)d_in[0];
    const float* W = (const float*)d_in[1];
    float* outp = (float*)d_out;
    float* Ap = outp + (size_t)NR * HD;  // A follows out in d_out
    char* ws = (char*)d_ws;
    ushort* Zb = (ushort*)ws;                                 // 2 MB
    ushort* ZbT = (ushort*)(ws + (size_t)NR * HD * 2);        // 2 MB
    float* rowsum = (float*)(ws + (size_t)NR * HD * 4);       // 32 KB

    (void)hipMemsetAsync(outp, 0, (size_t)NR * HD * sizeof(float), stream);
    (void)hipMemsetAsync(rowsum, 0, NR * sizeof(float), stream);
    k_z<<<dim3(NR / 32), dim3(256), 0, stream>>>(X, W, Zb, ZbT);
    k_rowsum<<<dim3(1024), dim3(256), 0, stream>>>(Zb, rowsum);
    k_main<<<dim3(1024), dim3(256), 0, stream>>>(Zb, ZbT, rowsum, outp, Ap);
}

// Round 6
// 370.103 us; speedup vs baseline: 1.2335x; 1.2335x over previous
//
#include <hip/hip_runtime.h>

// AdaptiveGraph on MI355X — v6: barrier surgery on k_main.
// Evidence (R4 rocprof): k_main 170us, MfmaUtil 7.8%, Occ 21.5%, 287MB written at 1.7TB/s
// -> latency-bound on 3 full-drain barriers/iter at 2 blocks/CU.
// Changes vs R4/R5 (k_main only; identical math, identical FP order):
//  - double-buffered ZC and PT -> ONE __syncthreads per 64-col iteration;
//  - ZCT staging deleted: U's B-operand (Bz) loaded per-iter straight from L2-resident ZbT
//    (identical addresses the ZCT tile held);
//  - next ZC tile prefetched into regs before S-phase, ds_written before the barrier;
//  - A-stores (nontemporal) deferred until AFTER the barrier so its vmcnt(0) drain
//    never waits on HBM store completion;
//  - LDS 53.2KB -> 3 blocks/CU, grid 1024.
// K1: Z = X W^T (bf16 MFMA hi/lo split). K2: rowsum (R5 version, grid 1024).
// K3: S^T recompute -> A=relu(S)*rsinv (nt stores) + out += P@Z, atomicAdd.

#define NR 8192
#define KD 256
#define HD 128

typedef short v8s __attribute__((ext_vector_type(8)));
typedef float v4f __attribute__((ext_vector_type(4)));

static __device__ __forceinline__ ushort f2bf(float f) {
    union { float f; unsigned u; } c; c.f = f;
    unsigned u = c.u;
    u += 0x7fffu + ((u >> 16) & 1u);  // RNE; inputs finite
    return (ushort)(u >> 16);
}
static __device__ __forceinline__ float bf2f(ushort b) {
    union { unsigned u; float f; } c; c.u = ((unsigned)b) << 16; return c.f;
}
static __device__ __forceinline__ unsigned pk2(float a, float b) {
    union { float f; unsigned u; } x, y; x.f = a; y.f = b;
    unsigned ua = x.u + 0x7fffu + ((x.u >> 16) & 1u);
    unsigned ub = y.u + 0x7fffu + ((y.u >> 16) & 1u);
    return (ua >> 16) | (ub & 0xffff0000u);
}

// ---------------- K1: Z = X @ W^T (MFMA, hi/lo bf16 split) ----------------
__global__ __launch_bounds__(256) void k_z(const float* __restrict__ X,
                                           const float* __restrict__ W,
                                           ushort* __restrict__ Zb,
                                           ushort* __restrict__ ZbT) {
    __shared__ ushort Xhi[32][264];
    __shared__ ushort Xlo[32][264];
    int tid = threadIdx.x, lane = tid & 63, wave = tid >> 6;
    int lm = lane & 15, lq = lane >> 4;
    int n0 = blockIdx.x * 32;
    int hbase = wave * 32;
    v8s Whi[2][8], Wlo[2][8];
#pragma unroll
    for (int hi = 0; hi < 2; ++hi) {
        const float* wp = W + (hbase + hi * 16 + lm) * KD + lq * 8;
#pragma unroll
        for (int ks = 0; ks < 8; ++ks) {
            float4 w0 = *(const float4*)(wp + ks * 32);
            float4 w1 = *(const float4*)(wp + ks * 32 + 4);
            float wv[8] = {w0.x, w0.y, w0.z, w0.w, w1.x, w1.y, w1.z, w1.w};
#pragma unroll
            for (int j = 0; j < 8; ++j) {
                ushort h = f2bf(wv[j]);
                Whi[hi][ks][j] = (short)h;
                Wlo[hi][ks][j] = (short)f2bf(wv[j] - bf2f(h));
            }
        }
    }
#pragma unroll
    for (int t = 0; t < 8; ++t) {
        int idx = tid + t * 256;
        int r = idx >> 6, c4 = (idx & 63) * 4;
        float4 x = *(const float4*)(X + (size_t)(n0 + r) * KD + c4);
        ushort h0 = f2bf(x.x), h1 = f2bf(x.y), h2 = f2bf(x.z), h3 = f2bf(x.w);
        unsigned a = ((unsigned)h0) | ((unsigned)h1 << 16);
        unsigned b = ((unsigned)h2) | ((unsigned)h3 << 16);
        unsigned c = ((unsigned)f2bf(x.x - bf2f(h0))) | ((unsigned)f2bf(x.y - bf2f(h1)) << 16);
        unsigned d = ((unsigned)f2bf(x.z - bf2f(h2))) | ((unsigned)f2bf(x.w - bf2f(h3)) << 16);
        *(uint2*)&Xhi[r][c4] = make_uint2(a, b);
        *(uint2*)&Xlo[r][c4] = make_uint2(c, d);
    }
    __syncthreads();
#pragma unroll
    for (int ni = 0; ni < 2; ++ni) {
        v8s Ah[8], Al[8];
#pragma unroll
        for (int ks = 0; ks < 8; ++ks) {
            Ah[ks] = *(const v8s*)&Xhi[ni * 16 + lm][ks * 32 + lq * 8];
            Al[ks] = *(const v8s*)&Xlo[ni * 16 + lm][ks * 32 + lq * 8];
        }
        v4f acc[2] = {{0.f, 0.f, 0.f, 0.f}, {0.f, 0.f, 0.f, 0.f}};
#pragma unroll
        for (int ks = 0; ks < 8; ++ks)
#pragma unroll
            for (int hi = 0; hi < 2; ++hi) {
                acc[hi] = __builtin_amdgcn_mfma_f32_16x16x32_bf16(Ah[ks], Whi[hi][ks], acc[hi], 0, 0, 0);
                acc[hi] = __builtin_amdgcn_mfma_f32_16x16x32_bf16(Ah[ks], Wlo[hi][ks], acc[hi], 0, 0, 0);
                acc[hi] = __builtin_amdgcn_mfma_f32_16x16x32_bf16(Al[ks], Whi[hi][ks], acc[hi], 0, 0, 0);
            }
#pragma unroll
        for (int hi = 0; hi < 2; ++hi) {
            int h = hbase + hi * 16 + lm;
            int nb = n0 + ni * 16 + lq * 4;
            ushort b0 = f2bf(acc[hi][0]), b1 = f2bf(acc[hi][1]);
            ushort b2 = f2bf(acc[hi][2]), b3 = f2bf(acc[hi][3]);
            Zb[(size_t)(nb + 0) * HD + h] = b0;
            Zb[(size_t)(nb + 1) * HD + h] = b1;
            Zb[(size_t)(nb + 2) * HD + h] = b2;
            Zb[(size_t)(nb + 3) * HD + h] = b3;
            *(uint2*)&ZbT[(size_t)h * NR + nb] =
                make_uint2(((unsigned)b0) | ((unsigned)b1 << 16), ((unsigned)b2) | ((unsigned)b3 << 16));
        }
    }
}

// ---------------- K2: rowsum (R5 version) ----------------
// grid 1024 = 64 rb x 16 cs; block tile 128r x (4 iters x 128c); 34.8 KB -> 4 blocks/CU.
__global__ __launch_bounds__(256) void k_rowsum(const ushort* __restrict__ Zb,
                                                float* __restrict__ rowsum) {
    __shared__ ushort ZC[128][136];
    int tid = threadIdx.x, lane = tid & 63, wave = tid >> 6;
    int lm = lane & 15, lq = lane >> 4;
    int rb = blockIdx.x >> 4, cs = blockIdx.x & 15;
    int row0 = rb * 128, cstart = cs * 512;
    int wr2 = wave >> 1, wc2 = wave & 1;
    v8s Bfr[4][4];
#pragma unroll
    for (int ri = 0; ri < 4; ++ri)
#pragma unroll
        for (int ks = 0; ks < 4; ++ks)
            Bfr[ri][ks] =
                *(const v8s*)(Zb + (size_t)(row0 + wr2 * 64 + ri * 16 + lm) * HD + ks * 32 + lq * 8);
    float rs[4] = {0.f, 0.f, 0.f, 0.f};
    for (int it = 0; it < 4; ++it) {
        int c0 = cstart + it * 128;
        __syncthreads();
#pragma unroll
        for (int t = 0; t < 8; ++t) {
            int idx = tid + t * 256;
            int r = idx >> 4, c8 = (idx & 15) * 8;
            *(uint4*)&ZC[r][c8] = *(const uint4*)(Zb + (size_t)(c0 + r) * HD + c8);
        }
        __syncthreads();
#pragma unroll
        for (int ci = 0; ci < 4; ++ci) {
            v8s Af[4];
#pragma unroll
            for (int ks = 0; ks < 4; ++ks)
                Af[ks] = *(const v8s*)&ZC[wc2 * 64 + ci * 16 + lm][ks * 32 + lq * 8];
            v4f acc[4] = {{0.f,0.f,0.f,0.f},{0.f,0.f,0.f,0.f},{0.f,0.f,0.f,0.f},{0.f,0.f,0.f,0.f}};
#pragma unroll
            for (int ks = 0; ks < 4; ++ks)
#pragma unroll
                for (int ri = 0; ri < 4; ++ri)
                    acc[ri] = __builtin_amdgcn_mfma_f32_16x16x32_bf16(Af[ks], Bfr[ri][ks], acc[ri], 0, 0, 0);
#pragma unroll
            for (int ri = 0; ri < 4; ++ri)
                rs[ri] += fmaxf(acc[ri][0], 0.f) + fmaxf(acc[ri][1], 0.f) +
                          fmaxf(acc[ri][2], 0.f) + fmaxf(acc[ri][3], 0.f);
        }
    }
#pragma unroll
    for (int ri = 0; ri < 4; ++ri) {
        float v = rs[ri];
        v += __shfl_xor(v, 16, 64);
        v += __shfl_xor(v, 32, 64);
        if (lq == 0) atomicAdd(&rowsum[row0 + wr2 * 64 + ri * 16 + lm], v);
    }
}

// ---------------- K3: A write + out accumulate — 1 barrier/iter ----------------
// grid 1024 = 128 rb x 8 cs; block tile 64r x (16 iters x 64c).
// LDS: ZC[2] (34.0KB) + PT[2] (18.4KB) = 53.2KB -> 3 blocks/CU.
__global__ __launch_bounds__(256) void k_main(const ushort* __restrict__ Zb,
                                              const ushort* __restrict__ ZbT,
                                              const float* __restrict__ rowsum,
                                              float* __restrict__ outp,
                                              float* __restrict__ Ap) {
    __shared__ ushort ZC[2][64][136];
    __shared__ ushort PT[2][64][72];
    int tid = threadIdx.x, lane = tid & 63, wave = tid >> 6;
    int lm = lane & 15, lq = lane >> 4;
    int rb = blockIdx.x >> 3, cs = blockIdx.x & 7;
    int row0 = rb * 64, colb = cs * 1024;
    int wr2 = wave >> 1, wc2 = wave & 1;
    v8s Bfr[2][4];  // one-time reg B-frags (rows of this strip)
#pragma unroll
    for (int ri = 0; ri < 2; ++ri)
#pragma unroll
        for (int ks = 0; ks < 4; ++ks)
            Bfr[ri][ks] =
                *(const v8s*)(Zb + (size_t)(row0 + wr2 * 32 + ri * 16 + lm) * HD + ks * 32 + lq * 8);
    float rsv[2];
#pragma unroll
    for (int ri = 0; ri < 2; ++ri)
        rsv[ri] = 1.0f / (rowsum[row0 + wr2 * 32 + ri * 16 + lm] + 1e-6f);
    v4f U[2][4];
#pragma unroll
    for (int ri = 0; ri < 2; ++ri)
#pragma unroll
        for (int hi = 0; hi < 4; ++hi) U[ri][hi] = (v4f){0.f, 0.f, 0.f, 0.f};

    // prologue: stage ZC[0]
#pragma unroll
    for (int t = 0; t < 4; ++t) {
        int idx = tid + t * 256;
        int r = idx >> 4, c8 = (idx & 15) * 8;
        *(uint4*)&ZC[0][r][c8] = *(const uint4*)(Zb + (size_t)(colb + r) * HD + c8);
    }
    __syncthreads();

    float* ap0 = Ap + (size_t)(row0 + wr2 * 32 + lm) * NR + colb + wc2 * 32 + lq * 4;
    float* ap1 = ap0 + (size_t)16 * NR;

    for (int it = 0; it < 16; ++it) {
        int cur = it & 1;
        int c0 = colb + it * 64;
        // prefetch next ZC tile into regs (drains at this iter's barrier)
        uint4 sr[4];
        if (it < 15) {
#pragma unroll
            for (int t = 0; t < 4; ++t) {
                int idx = tid + t * 256;
                int r = idx >> 4, c8 = (idx & 15) * 8;
                sr[t] = *(const uint4*)(Zb + (size_t)(c0 + 64 + r) * HD + c8);
            }
        }
        // U-phase B-operand straight from L2-resident ZbT (same values old ZCT tile held)
        v8s Bz[4][2];
#pragma unroll
        for (int hi = 0; hi < 4; ++hi)
#pragma unroll
            for (int ks = 0; ks < 2; ++ks)
                Bz[hi][ks] = *(const v8s*)(ZbT + (size_t)(wc2 * 64 + hi * 16 + lm) * NR + c0 +
                                           ks * 32 + lq * 8);
        // S phase: S^T = (ZC as A) x (Bfr as B); D: r=lm, c=lq*4+reg
        v4f avst[2][2];  // deferred A-store values [ci][r-half]
#pragma unroll
        for (int ci = 0; ci < 2; ++ci) {
            v8s Af[4];
#pragma unroll
            for (int ks = 0; ks < 4; ++ks)
                Af[ks] = *(const v8s*)&ZC[cur][wc2 * 32 + ci * 16 + lm][ks * 32 + lq * 8];
            v4f S0 = {0.f, 0.f, 0.f, 0.f}, S1 = {0.f, 0.f, 0.f, 0.f};
#pragma unroll
            for (int ks = 0; ks < 4; ++ks) {
                S0 = __builtin_amdgcn_mfma_f32_16x16x32_bf16(Af[ks], Bfr[0][ks], S0, 0, 0, 0);
                S1 = __builtin_amdgcn_mfma_f32_16x16x32_bf16(Af[ks], Bfr[1][ks], S1, 0, 0, 0);
            }
            int cb = wc2 * 32 + ci * 16 + lq * 4;
            {
                v4f av;
                av[0] = fmaxf(S0[0], 0.f) * rsv[0]; av[1] = fmaxf(S0[1], 0.f) * rsv[0];
                av[2] = fmaxf(S0[2], 0.f) * rsv[0]; av[3] = fmaxf(S0[3], 0.f) * rsv[0];
                avst[ci][0] = av;
                *(uint2*)&PT[cur][wr2 * 32 + lm][cb] = make_uint2(pk2(av[0], av[1]), pk2(av[2], av[3]));
            }
            {
                v4f av;
                av[0] = fmaxf(S1[0], 0.f) * rsv[1]; av[1] = fmaxf(S1[1], 0.f) * rsv[1];
                av[2] = fmaxf(S1[2], 0.f) * rsv[1]; av[3] = fmaxf(S1[3], 0.f) * rsv[1];
                avst[ci][1] = av;
                *(uint2*)&PT[cur][wr2 * 32 + 16 + lm][cb] =
                    make_uint2(pk2(av[0], av[1]), pk2(av[2], av[3]));
            }
        }
        // write next ZC tile (other buffer; its last readers finished before prev barrier)
        if (it < 15) {
#pragma unroll
            for (int t = 0; t < 4; ++t) {
                int idx = tid + t * 256;
                int r = idx >> 4, c8 = (idx & 15) * 8;
                *(uint4*)&ZC[cur ^ 1][r][c8] = sr[t];
            }
        }
        __syncthreads();  // THE barrier: PT[cur] + ZC[nxt] ready
        // deferred A-stores: drain at NEXT iter's barrier, a full phase away
#pragma unroll
        for (int ci = 0; ci < 2; ++ci) {
            __builtin_nontemporal_store(avst[ci][0], (v4f*)(ap0 + ci * 16));
            __builtin_nontemporal_store(avst[ci][1], (v4f*)(ap1 + ci * 16));
        }
        // U phase: U[r][h] += P[r][c] * Z[c][h]; A = PT frag, B = Bz regs
#pragma unroll
        for (int ks = 0; ks < 2; ++ks) {
            v8s P0 = *(const v8s*)&PT[cur][wr2 * 32 + lm][ks * 32 + lq * 8];
            v8s P1 = *(const v8s*)&PT[cur][wr2 * 32 + 16 + lm][ks * 32 + lq * 8];
#pragma unroll
            for (int hi = 0; hi < 4; ++hi) {
                U[0][hi] = __builtin_amdgcn_mfma_f32_16x16x32_bf16(P0, Bz[hi][ks], U[0][hi], 0, 0, 0);
                U[1][hi] = __builtin_amdgcn_mfma_f32_16x16x32_bf16(P1, Bz[hi][ks], U[1][hi], 0, 0, 0);
            }
        }
        ap0 += 64;
        ap1 += 64;
    }
#pragma unroll
    for (int ri = 0; ri < 2; ++ri)
#pragma unroll
        for (int hi = 0; hi < 4; ++hi)
#pragma unroll
            for (int j = 0; j < 4; ++j)
                atomicAdd(&outp[(size_t)(row0 + wr2 * 32 + ri * 16 + lq * 4 + j) * HD +
                                wc2 * 64 + hi * 16 + lm],
                          U[ri][hi][j]);
}

extern "C" void kernel_launch(void* const* d_in, const int* in_sizes, int n_in,
                              void* d_out, int out_size, void* d_ws, size_t ws_size,
                              hipStream_t stream) {
    (void)in_sizes; (void)n_in; (void)out_size; (void)ws_size;
    const float* X = (const float*)d_in[0];
    const float* W = (const float*)d_in[1];
    float* outp = (float*)d_out;
    float* Ap = outp + (size_t)NR * HD;  // A follows out in d_out
    char* ws = (char*)d_ws;
    ushort* Zb = (ushort*)ws;                                 // 2 MB
    ushort* ZbT = (ushort*)(ws + (size_t)NR * HD * 2);        // 2 MB
    float* rowsum = (float*)(ws + (size_t)NR * HD * 4);       // 32 KB

    (void)hipMemsetAsync(outp, 0, (size_t)NR * HD * sizeof(float), stream);
    (void)hipMemsetAsync(rowsum, 0, NR * sizeof(float), stream);
    k_z<<<dim3(NR / 32), dim3(256), 0, stream>>>(X, W, Zb, ZbT);
    k_rowsum<<<dim3(1024), dim3(256), 0, stream>>>(Zb, rowsum);
    k_main<<<dim3(1024), dim3(256), 0, stream>>>(Zb, ZbT, rowsum, outp, Ap);
}

// Round 8
// 361.921 us; speedup vs baseline: 1.2614x; 1.0226x over previous
//
#include <hip/hip_runtime.h>

// AdaptiveGraph on MI355X — v8: R6 base (370us, proven) + R6-surgery on k_rowsum/k_z.
// R7 lesson: ws_size in [12,40)MB -> OOB Vp corrupted results. ws footprint kept at 8.03MB.
// k_main: BYTE-IDENTICAL to R6 (1 barrier/iter, dbuf ZC/PT, deferred nt A-stores, outp atomics).
// k_rowsum: R6 pattern applied — 64-col dbuf tiles ZC[2][64][136] (34.8KB, 4 blocks/CU),
//           reg-prefetch, ONE barrier/iter (was 2), waves own 32 rows.
// k_z: grid 256->512 (16 rows/block): was 1 block/CU grid-starved.

#define NR 8192
#define KD 256
#define HD 128

typedef short v8s __attribute__((ext_vector_type(8)));
typedef float v4f __attribute__((ext_vector_type(4)));

static __device__ __forceinline__ ushort f2bf(float f) {
    union { float f; unsigned u; } c; c.f = f;
    unsigned u = c.u;
    u += 0x7fffu + ((u >> 16) & 1u);  // RNE; inputs finite
    return (ushort)(u >> 16);
}
static __device__ __forceinline__ float bf2f(ushort b) {
    union { unsigned u; float f; } c; c.u = ((unsigned)b) << 16; return c.f;
}
static __device__ __forceinline__ unsigned pk2(float a, float b) {
    union { float f; unsigned u; } x, y; x.f = a; y.f = b;
    unsigned ua = x.u + 0x7fffu + ((x.u >> 16) & 1u);
    unsigned ub = y.u + 0x7fffu + ((y.u >> 16) & 1u);
    return (ua >> 16) | (ub & 0xffff0000u);
}

// ---------------- K1: Z = X @ W^T (MFMA, hi/lo bf16 split) ----------------
// grid 512 blocks x 256 thr; block = 16 rows of X; wave owns 32 h-columns.
__global__ __launch_bounds__(256) void k_z(const float* __restrict__ X,
                                           const float* __restrict__ W,
                                           ushort* __restrict__ Zb,
                                           ushort* __restrict__ ZbT) {
    __shared__ ushort Xhi[16][264];
    __shared__ ushort Xlo[16][264];
    int tid = threadIdx.x, lane = tid & 63, wave = tid >> 6;
    int lm = lane & 15, lq = lane >> 4;
    int n0 = blockIdx.x * 16;
    int hbase = wave * 32;
    v8s Whi[2][8], Wlo[2][8];
#pragma unroll
    for (int hi = 0; hi < 2; ++hi) {
        const float* wp = W + (hbase + hi * 16 + lm) * KD + lq * 8;
#pragma unroll
        for (int ks = 0; ks < 8; ++ks) {
            float4 w0 = *(const float4*)(wp + ks * 32);
            float4 w1 = *(const float4*)(wp + ks * 32 + 4);
            float wv[8] = {w0.x, w0.y, w0.z, w0.w, w1.x, w1.y, w1.z, w1.w};
#pragma unroll
            for (int j = 0; j < 8; ++j) {
                ushort h = f2bf(wv[j]);
                Whi[hi][ks][j] = (short)h;
                Wlo[hi][ks][j] = (short)f2bf(wv[j] - bf2f(h));
            }
        }
    }
    // stage X tile 16x256 as hi/lo bf16
#pragma unroll
    for (int t = 0; t < 4; ++t) {
        int idx = tid + t * 256;
        int r = idx >> 6, c4 = (idx & 63) * 4;
        float4 x = *(const float4*)(X + (size_t)(n0 + r) * KD + c4);
        ushort h0 = f2bf(x.x), h1 = f2bf(x.y), h2 = f2bf(x.z), h3 = f2bf(x.w);
        unsigned a = ((unsigned)h0) | ((unsigned)h1 << 16);
        unsigned b = ((unsigned)h2) | ((unsigned)h3 << 16);
        unsigned c = ((unsigned)f2bf(x.x - bf2f(h0))) | ((unsigned)f2bf(x.y - bf2f(h1)) << 16);
        unsigned d = ((unsigned)f2bf(x.z - bf2f(h2))) | ((unsigned)f2bf(x.w - bf2f(h3)) << 16);
        *(uint2*)&Xhi[r][c4] = make_uint2(a, b);
        *(uint2*)&Xlo[r][c4] = make_uint2(c, d);
    }
    __syncthreads();
    {
        v8s Ah[8], Al[8];
#pragma unroll
        for (int ks = 0; ks < 8; ++ks) {
            Ah[ks] = *(const v8s*)&Xhi[lm][ks * 32 + lq * 8];
            Al[ks] = *(const v8s*)&Xlo[lm][ks * 32 + lq * 8];
        }
        v4f acc[2] = {{0.f, 0.f, 0.f, 0.f}, {0.f, 0.f, 0.f, 0.f}};
#pragma unroll
        for (int ks = 0; ks < 8; ++ks)
#pragma unroll
            for (int hi = 0; hi < 2; ++hi) {
                acc[hi] = __builtin_amdgcn_mfma_f32_16x16x32_bf16(Ah[ks], Whi[hi][ks], acc[hi], 0, 0, 0);
                acc[hi] = __builtin_amdgcn_mfma_f32_16x16x32_bf16(Ah[ks], Wlo[hi][ks], acc[hi], 0, 0, 0);
                acc[hi] = __builtin_amdgcn_mfma_f32_16x16x32_bf16(Al[ks], Whi[hi][ks], acc[hi], 0, 0, 0);
            }
#pragma unroll
        for (int hi = 0; hi < 2; ++hi) {
            int h = hbase + hi * 16 + lm;   // D: col=lm -> h, row=lq*4+j -> n
            int nb = n0 + lq * 4;
            ushort b0 = f2bf(acc[hi][0]), b1 = f2bf(acc[hi][1]);
            ushort b2 = f2bf(acc[hi][2]), b3 = f2bf(acc[hi][3]);
            Zb[(size_t)(nb + 0) * HD + h] = b0;
            Zb[(size_t)(nb + 1) * HD + h] = b1;
            Zb[(size_t)(nb + 2) * HD + h] = b2;
            Zb[(size_t)(nb + 3) * HD + h] = b3;
            *(uint2*)&ZbT[(size_t)h * NR + nb] =
                make_uint2(((unsigned)b0) | ((unsigned)b1 << 16), ((unsigned)b2) | ((unsigned)b3 << 16));
        }
    }
}

// ---------------- K2: rowsum — 1 barrier/iter ----------------
// grid 1024 = 64 rb x 16 cs; block = 128 rows x (8 iters x 64 cols); wave owns 32 rows.
// LDS ZC[2][64][136] = 34.8 KB -> 4 blocks/CU. Bfr one-time from global.
__global__ __launch_bounds__(256) void k_rowsum(const ushort* __restrict__ Zb,
                                                float* __restrict__ rowsum) {
    __shared__ ushort ZC[2][64][136];
    int tid = threadIdx.x, lane = tid & 63, wave = tid >> 6;
    int lm = lane & 15, lq = lane >> 4;
    int rb = blockIdx.x >> 4, cs = blockIdx.x & 15;
    int row0 = rb * 128, cstart = cs * 512;
    v8s Bfr[2][4];  // this wave's 32 rows (B-operand), one-time global load
#pragma unroll
    for (int ri = 0; ri < 2; ++ri)
#pragma unroll
        for (int ks = 0; ks < 4; ++ks)
            Bfr[ri][ks] =
                *(const v8s*)(Zb + (size_t)(row0 + wave * 32 + ri * 16 + lm) * HD + ks * 32 + lq * 8);
    float rs[2] = {0.f, 0.f};
    // prologue: stage ZC[0] (cols cstart..cstart+64)
#pragma unroll
    for (int t = 0; t < 4; ++t) {
        int idx = tid + t * 256;
        int r = idx >> 4, c8 = (idx & 15) * 8;
        *(uint4*)&ZC[0][r][c8] = *(const uint4*)(Zb + (size_t)(cstart + r) * HD + c8);
    }
    __syncthreads();
    for (int it = 0; it < 8; ++it) {
        int cur = it & 1;
        int c0 = cstart + it * 64;
        uint4 sr[4];
        if (it < 7) {
#pragma unroll
            for (int t = 0; t < 4; ++t) {
                int idx = tid + t * 256;
                int r = idx >> 4, c8 = (idx & 15) * 8;
                sr[t] = *(const uint4*)(Zb + (size_t)(c0 + 64 + r) * HD + c8);
            }
        }
#pragma unroll
        for (int ci = 0; ci < 4; ++ci) {
            v8s Af[4];
#pragma unroll
            for (int ks = 0; ks < 4; ++ks)
                Af[ks] = *(const v8s*)&ZC[cur][ci * 16 + lm][ks * 32 + lq * 8];
            v4f a0 = {0.f, 0.f, 0.f, 0.f}, a1 = {0.f, 0.f, 0.f, 0.f};
#pragma unroll
            for (int ks = 0; ks < 4; ++ks) {
                a0 = __builtin_amdgcn_mfma_f32_16x16x32_bf16(Af[ks], Bfr[0][ks], a0, 0, 0, 0);
                a1 = __builtin_amdgcn_mfma_f32_16x16x32_bf16(Af[ks], Bfr[1][ks], a1, 0, 0, 0);
            }
            rs[0] += fmaxf(a0[0], 0.f) + fmaxf(a0[1], 0.f) + fmaxf(a0[2], 0.f) + fmaxf(a0[3], 0.f);
            rs[1] += fmaxf(a1[0], 0.f) + fmaxf(a1[1], 0.f) + fmaxf(a1[2], 0.f) + fmaxf(a1[3], 0.f);
        }
        if (it < 7) {
#pragma unroll
            for (int t = 0; t < 4; ++t) {
                int idx = tid + t * 256;
                int r = idx >> 4, c8 = (idx & 15) * 8;
                *(uint4*)&ZC[cur ^ 1][r][c8] = sr[t];
            }
        }
        __syncthreads();
    }
#pragma unroll
    for (int ri = 0; ri < 2; ++ri) {
        float v = rs[ri];
        v += __shfl_xor(v, 16, 64);
        v += __shfl_xor(v, 32, 64);
        if (lq == 0) atomicAdd(&rowsum[row0 + wave * 32 + ri * 16 + lm], v);
    }
}

// ---------------- K3: A write + out accumulate — 1 barrier/iter (R6, byte-identical) ----------------
// grid 1024 = 128 rb x 8 cs; block tile 64r x (16 iters x 64c). LDS 53.2KB -> 3 blocks/CU.
__global__ __launch_bounds__(256) void k_main(const ushort* __restrict__ Zb,
                                              const ushort* __restrict__ ZbT,
                                              const float* __restrict__ rowsum,
                                              float* __restrict__ outp,
                                              float* __restrict__ Ap) {
    __shared__ ushort ZC[2][64][136];
    __shared__ ushort PT[2][64][72];
    int tid = threadIdx.x, lane = tid & 63, wave = tid >> 6;
    int lm = lane & 15, lq = lane >> 4;
    int rb = blockIdx.x >> 3, cs = blockIdx.x & 7;
    int row0 = rb * 64, colb = cs * 1024;
    int wr2 = wave >> 1, wc2 = wave & 1;
    v8s Bfr[2][4];  // one-time reg B-frags (rows of this strip)
#pragma unroll
    for (int ri = 0; ri < 2; ++ri)
#pragma unroll
        for (int ks = 0; ks < 4; ++ks)
            Bfr[ri][ks] =
                *(const v8s*)(Zb + (size_t)(row0 + wr2 * 32 + ri * 16 + lm) * HD + ks * 32 + lq * 8);
    float rsv[2];
#pragma unroll
    for (int ri = 0; ri < 2; ++ri)
        rsv[ri] = 1.0f / (rowsum[row0 + wr2 * 32 + ri * 16 + lm] + 1e-6f);
    v4f U[2][4];
#pragma unroll
    for (int ri = 0; ri < 2; ++ri)
#pragma unroll
        for (int hi = 0; hi < 4; ++hi) U[ri][hi] = (v4f){0.f, 0.f, 0.f, 0.f};

    // prologue: stage ZC[0]
#pragma unroll
    for (int t = 0; t < 4; ++t) {
        int idx = tid + t * 256;
        int r = idx >> 4, c8 = (idx & 15) * 8;
        *(uint4*)&ZC[0][r][c8] = *(const uint4*)(Zb + (size_t)(colb + r) * HD + c8);
    }
    __syncthreads();

    float* ap0 = Ap + (size_t)(row0 + wr2 * 32 + lm) * NR + colb + wc2 * 32 + lq * 4;
    float* ap1 = ap0 + (size_t)16 * NR;

    for (int it = 0; it < 16; ++it) {
        int cur = it & 1;
        int c0 = colb + it * 64;
        uint4 sr[4];
        if (it < 15) {
#pragma unroll
            for (int t = 0; t < 4; ++t) {
                int idx = tid + t * 256;
                int r = idx >> 4, c8 = (idx & 15) * 8;
                sr[t] = *(const uint4*)(Zb + (size_t)(c0 + 64 + r) * HD + c8);
            }
        }
        v8s Bz[4][2];
#pragma unroll
        for (int hi = 0; hi < 4; ++hi)
#pragma unroll
            for (int ks = 0; ks < 2; ++ks)
                Bz[hi][ks] = *(const v8s*)(ZbT + (size_t)(wc2 * 64 + hi * 16 + lm) * NR + c0 +
                                           ks * 32 + lq * 8);
        v4f avst[2][2];  // deferred A-store values [ci][r-half]
#pragma unroll
        for (int ci = 0; ci < 2; ++ci) {
            v8s Af[4];
#pragma unroll
            for (int ks = 0; ks < 4; ++ks)
                Af[ks] = *(const v8s*)&ZC[cur][wc2 * 32 + ci * 16 + lm][ks * 32 + lq * 8];
            v4f S0 = {0.f, 0.f, 0.f, 0.f}, S1 = {0.f, 0.f, 0.f, 0.f};
#pragma unroll
            for (int ks = 0; ks < 4; ++ks) {
                S0 = __builtin_amdgcn_mfma_f32_16x16x32_bf16(Af[ks], Bfr[0][ks], S0, 0, 0, 0);
                S1 = __builtin_amdgcn_mfma_f32_16x16x32_bf16(Af[ks], Bfr[1][ks], S1, 0, 0, 0);
            }
            int cb = wc2 * 32 + ci * 16 + lq * 4;
            {
                v4f av;
                av[0] = fmaxf(S0[0], 0.f) * rsv[0]; av[1] = fmaxf(S0[1], 0.f) * rsv[0];
                av[2] = fmaxf(S0[2], 0.f) * rsv[0]; av[3] = fmaxf(S0[3], 0.f) * rsv[0];
                avst[ci][0] = av;
                *(uint2*)&PT[cur][wr2 * 32 + lm][cb] = make_uint2(pk2(av[0], av[1]), pk2(av[2], av[3]));
            }
            {
                v4f av;
                av[0] = fmaxf(S1[0], 0.f) * rsv[1]; av[1] = fmaxf(S1[1], 0.f) * rsv[1];
                av[2] = fmaxf(S1[2], 0.f) * rsv[1]; av[3] = fmaxf(S1[3], 0.f) * rsv[1];
                avst[ci][1] = av;
                *(uint2*)&PT[cur][wr2 * 32 + 16 + lm][cb] =
                    make_uint2(pk2(av[0], av[1]), pk2(av[2], av[3]));
            }
        }
        if (it < 15) {
#pragma unroll
            for (int t = 0; t < 4; ++t) {
                int idx = tid + t * 256;
                int r = idx >> 4, c8 = (idx & 15) * 8;
                *(uint4*)&ZC[cur ^ 1][r][c8] = sr[t];
            }
        }
        __syncthreads();  // THE barrier: PT[cur] + ZC[nxt] ready
#pragma unroll
        for (int ci = 0; ci < 2; ++ci) {
            __builtin_nontemporal_store(avst[ci][0], (v4f*)(ap0 + ci * 16));
            __builtin_nontemporal_store(avst[ci][1], (v4f*)(ap1 + ci * 16));
        }
#pragma unroll
        for (int ks = 0; ks < 2; ++ks) {
            v8s P0 = *(const v8s*)&PT[cur][wr2 * 32 + lm][ks * 32 + lq * 8];
            v8s P1 = *(const v8s*)&PT[cur][wr2 * 32 + 16 + lm][ks * 32 + lq * 8];
#pragma unroll
            for (int hi = 0; hi < 4; ++hi) {
                U[0][hi] = __builtin_amdgcn_mfma_f32_16x16x32_bf16(P0, Bz[hi][ks], U[0][hi], 0, 0, 0);
                U[1][hi] = __builtin_amdgcn_mfma_f32_16x16x32_bf16(P1, Bz[hi][ks], U[1][hi], 0, 0, 0);
            }
        }
        ap0 += 64;
        ap1 += 64;
    }
#pragma unroll
    for (int ri = 0; ri < 2; ++ri)
#pragma unroll
        for (int hi = 0; hi < 4; ++hi)
#pragma unroll
            for (int j = 0; j < 4; ++j)
                atomicAdd(&outp[(size_t)(row0 + wr2 * 32 + ri * 16 + lq * 4 + j) * HD +
                                wc2 * 64 + hi * 16 + lm],
                          U[ri][hi][j]);
}

extern "C" void kernel_launch(void* const* d_in, const int* in_sizes, int n_in,
                              void* d_out, int out_size, void* d_ws, size_t ws_size,
                              hipStream_t stream) {
    (void)in_sizes; (void)n_in; (void)out_size; (void)ws_size;
    const float* X = (const float*)d_in[0];
    const float* W = (const float*)d_in[1];
    float* outp = (float*)d_out;
    float* Ap = outp + (size_t)NR * HD;  // A follows out in d_out
    char* ws = (char*)d_ws;
    ushort* Zb = (ushort*)ws;                                 // 2 MB
    ushort* ZbT = (ushort*)(ws + (size_t)NR * HD * 2);        // 2 MB
    float* rowsum = (float*)(ws + (size_t)NR * HD * 4);       // 32 KB  (ws total 8.03MB, proven)

    (void)hipMemsetAsync(outp, 0, (size_t)NR * HD * sizeof(float), stream);
    (void)hipMemsetAsync(rowsum, 0, NR * sizeof(float), stream);
    k_z<<<dim3(NR / 16), dim3(256), 0, stream>>>(X, W, Zb, ZbT);
    k_rowsum<<<dim3(1024), dim3(256), 0, stream>>>(Zb, rowsum);
    k_main<<<dim3(1024), dim3(256), 0, stream>>>(Zb, ZbT, rowsum, outp, Ap);
}